// Round 25
// baseline (175.980 us; speedup 1.0000x reference)
//
#include <hip/hip_runtime.h>
#include <cstdint>
#include <cstddef>

#define NCENT   100000
#define DIM     128
#define BATCH   1024
#define NCLASS  100
#define KNEIGH  200
#define GC      0.005f          // 1/(2*sigma^2), sigma=10
#define S_THR   75.0f           // static pre-filter on s; cut s in [38,58], slack >15
#define HIST_SZ 160
#define LIST_CAP 8192           // per-row list capacity; expected ~2800, worst ~4500
#define BAND_CAP 256            // band = 3 bins ~63-90 items; 256 ample
#define ROWS_PB  64             // rows per block in mfma (r19 proven)
#define LSLOTS   60             // per-(row,block) LDS slots + global fallback

typedef __attribute__((ext_vector_type(8))) short s8v;   // 8 bf16
typedef __attribute__((ext_vector_type(4))) float f4v;   // 4 f32 acc

static __device__ __forceinline__ unsigned short f2bf(float x) {
    uint32_t b = __float_as_uint(x);
    uint32_t r = (b + 0x7fffu + ((b >> 16) & 1u)) >> 16;   // RNE
    return (unsigned short)r;
}

// ---- replicate numpy AVX512 pairwise sum of x[k]^2, k=0..127 (round-3 verified) ----
__device__ __forceinline__ float np_sum128_sq(const float* __restrict__ x) {
#pragma clang fp contract(off)
    float v[16];
#pragma unroll
    for (int l = 0; l < 16; ++l) {
        float q0 = x[l]       * x[l];
        float q1 = x[16 + l]  * x[16 + l];
        float q2 = x[32 + l]  * x[32 + l];
        float q3 = x[48 + l]  * x[48 + l];
        float q4 = x[64 + l]  * x[64 + l];
        float q5 = x[80 + l]  * x[80 + l];
        float q6 = x[96 + l]  * x[96 + l];
        float q7 = x[112 + l] * x[112 + l];
        v[l] = ((q0 + q1) + (q2 + q3)) + ((q4 + q5) + (q6 + q7));
    }
    float t0 = v[0] + v[8],  t1 = v[1] + v[9],  t2 = v[2] + v[10], t3 = v[3] + v[11];
    float t4 = v[4] + v[12], t5 = v[5] + v[13], t6 = v[6] + v[14], t7 = v[7] + v[15];
    float u0 = t0 + t4, u1 = t1 + t5, u2 = t2 + t6, u3 = t3 + t7;
    float p0 = u0 + u2, p1 = u1 + u3;
    return p0 + p1;
}

// ---- prep: centres f32 -> bf16 + fp32 norms ----
__global__ __launch_bounds__(256) void prep_cent_kernel(
    const float* __restrict__ cent, unsigned short* __restrict__ centb,
    float* __restrict__ cnorm) {
    const int t = threadIdx.x;
    const int c = blockIdx.x * 32 + (t >> 3);
    const int p = t & 7;
    const float4* src = (const float4*)(cent + (size_t)c * DIM + p * 16);
    float s = 0.f;
    unsigned short tmp[16];
#pragma unroll
    for (int j = 0; j < 4; ++j) {
        float4 v = src[j];
        s += v.x * v.x + v.y * v.y + v.z * v.z + v.w * v.w;
        tmp[4 * j + 0] = f2bf(v.x); tmp[4 * j + 1] = f2bf(v.y);
        tmp[4 * j + 2] = f2bf(v.z); tmp[4 * j + 3] = f2bf(v.w);
    }
    s += __shfl_xor(s, 1); s += __shfl_xor(s, 2); s += __shfl_xor(s, 4);
    if (p == 0) cnorm[c] = s;
    uint4 o0, o1;
    o0.x = (uint32_t)tmp[0]  | ((uint32_t)tmp[1]  << 16);
    o0.y = (uint32_t)tmp[2]  | ((uint32_t)tmp[3]  << 16);
    o0.z = (uint32_t)tmp[4]  | ((uint32_t)tmp[5]  << 16);
    o0.w = (uint32_t)tmp[6]  | ((uint32_t)tmp[7]  << 16);
    o1.x = (uint32_t)tmp[8]  | ((uint32_t)tmp[9]  << 16);
    o1.y = (uint32_t)tmp[10] | ((uint32_t)tmp[11] << 16);
    o1.z = (uint32_t)tmp[12] | ((uint32_t)tmp[13] << 16);
    o1.w = (uint32_t)tmp[14] | ((uint32_t)tmp[15] << 16);
    uint4* dst = (uint4*)(centb + (size_t)c * DIM + p * 16);
    dst[0] = o0; dst[1] = o1;
}

// ---- prep: feat f32 -> bf16 + np-replicated |f|^2 per row; also zeroes listCnt ----
__global__ __launch_bounds__(256) void prep_feat_kernel(
    const float* __restrict__ feat, unsigned short* __restrict__ featb,
    float* __restrict__ fnrep, unsigned int* __restrict__ listCnt) {
    const int r = blockIdx.x * 256 + threadIdx.x;
    if (r >= BATCH) return;
    listCnt[r] = 0u;                     // replaces the separate hipMemsetAsync dispatch
    const float* fp = feat + (size_t)r * DIM;
    fnrep[r] = np_sum128_sq(fp);
    unsigned short* dst = featb + (size_t)r * DIM;
    for (int k = 0; k < DIM; ++k) dst[k] = f2bf(fp[k]);
}

// ---- coarse distance via bf16 MFMA (r22 champion: depth-1 prefetch, lazy-s epilogue) ----
// launch_bounds(256,3): 170-reg budget, no spill. Occupancy walls (measured):
//   (256,4) -> compiler squeezes to 64 VGPR and SPILLS (r23: WRITE 116MB, dur +4us)
//   more blocks/CU -> B-stripe L2 thrash (r12: FETCH 465MB)
//   depth-2 B pipe -> +regs +traffic (r21: +11us)
__global__ __launch_bounds__(256, 3) void mfma_coarse_kernel(
    const unsigned short* __restrict__ featb, const unsigned short* __restrict__ centb,
    const float* __restrict__ cnorm,
    unsigned long long* __restrict__ lists, unsigned int* __restrict__ listCnt) {
    __shared__ unsigned long long lbuf[ROWS_PB][LSLOTS];
    __shared__ unsigned int lcnt[ROWS_PB];
    __shared__ unsigned int gbase[ROWS_PB];
    __shared__ unsigned int gcnt[ROWS_PB];

    const int t = threadIdx.x;
    const int w = t >> 6;
    const int lane = t & 63;
    const int lrow = lane & 15;
    const int q = lane >> 4;
    const int lk = q * 8;
    const int row0 = blockIdx.y * ROWS_PB;
    const int colbase = blockIdx.x * 512;

    for (int i = t; i < ROWS_PB; i += 256) lcnt[i] = 0;

    s8v a[4][4];
#pragma unroll
    for (int rs = 0; rs < 4; ++rs)
#pragma unroll
        for (int ks = 0; ks < 4; ++ks)
            a[rs][ks] = *(const s8v*)(featb + (size_t)(row0 + rs * 16 + lrow) * DIM + ks * 32 + lk);

    __syncthreads();

    // prefetch it=0 B fragments + cnorm (depth-1, r20-proven)
    s8v b[4];
    float cn;
    {
        const int ccol = colbase + w * 16 + lrow;
        const int cc = ccol < NCENT ? ccol : NCENT - 1;
#pragma unroll
        for (int ks = 0; ks < 4; ++ks)
            b[ks] = *(const s8v*)(centb + (size_t)cc * DIM + ks * 32 + lk);
        cn = cnorm[cc];
    }

    for (int it = 0; it < 8; ++it) {
        const int ccol = colbase + it * 64 + w * 16 + lrow;
        const bool valid = (ccol < NCENT);

        s8v bc[4];
#pragma unroll
        for (int ks = 0; ks < 4; ++ks) bc[ks] = b[ks];
        const float cnc = cn;
        {
            const int itn = it + 1 < 8 ? it + 1 : 7;
            const int ccn = colbase + itn * 64 + w * 16 + lrow;
            const int cc2 = ccn < NCENT ? ccn : NCENT - 1;
#pragma unroll
            for (int ks = 0; ks < 4; ++ks)
                b[ks] = *(const s8v*)(centb + (size_t)cc2 * DIM + ks * 32 + lk);
            cn = cnorm[cc2];
        }

        f4v acc[4];
#pragma unroll
        for (int rs = 0; rs < 4; ++rs) acc[rs] = (f4v){0.f, 0.f, 0.f, 0.f};

#pragma unroll
        for (int ks = 0; ks < 4; ++ks) {
#pragma unroll
            for (int rs = 0; rs < 4; ++rs)
                acc[rs] = __builtin_amdgcn_mfma_f32_16x16x32_bf16(a[rs][ks], bc[ks], acc[rs], 0, 0, 0);
        }

        // epilogue: pass iff dot > (cn - S_THR)/2; s computed lazily for passers only
        const float thr = (cnc - S_THR) * 0.5f;
#pragma unroll
        for (int rs = 0; rs < 4; ++rs) {
#pragma unroll
            for (int j = 0; j < 4; ++j) {
                const float av = acc[rs][j];
                if (valid && av > thr) {            // ~2.8% of lanes
                    const float s = cnc - 2.0f * av;
                    const int lrowIdx = rs * 16 + q * 4 + j;
                    const unsigned long long val =
                        ((unsigned long long)__float_as_uint(s) << 32) | (unsigned)ccol;
                    unsigned pos = atomicAdd(&lcnt[lrowIdx], 1u);
                    if (pos < LSLOTS) {
                        lbuf[lrowIdx][pos] = val;
                    } else {
                        unsigned gp = atomicAdd(&listCnt[row0 + lrowIdx], 1u);
                        if (gp < LIST_CAP)
                            lists[(size_t)(row0 + lrowIdx) * LIST_CAP + gp] = val;
                    }
                }
            }
        }
    }
    __syncthreads();

    if (t < ROWS_PB) {
        unsigned c = lcnt[t];
        c = c < LSLOTS ? c : LSLOTS;
        gcnt[t] = c;
        gbase[t] = c ? atomicAdd(&listCnt[row0 + t], c) : 0u;
    }
    __syncthreads();
    {
        const int r = t >> 2, part = t & 3;
        const unsigned cnt = gcnt[r];
        for (unsigned sidx = (unsigned)part; sidx < cnt; sidx += 4) {
            const unsigned dstp = gbase[r] + sidx;
            if (dstp < LIST_CAP)
                lists[(size_t)(row0 + r) * LIST_CAP + dstp] = lbuf[r][sidx];
        }
    }
}

// ---- select+refine v3: bin-sandwich selection ----
// launch_bounds(512,8): 64-reg budget; measured use 56 VGPR (r19) -> no spill, and
// lifts residency from 2 to 4 blocks/CU (the (512,4) declaration capped Occ at ~31%).
__global__ __launch_bounds__(512, 8) void select_refine_kernel(
    const unsigned long long* __restrict__ lists, const unsigned int* __restrict__ listCnt,
    const float* __restrict__ feat, const float* __restrict__ cent,
    const float* __restrict__ fnrep,
    const float* __restrict__ kw, const int* __restrict__ labels,
    float* __restrict__ out) {

    __shared__ unsigned int h[HIST_SZ];
    __shared__ float fsh[DIM];
    __shared__ float p[NCLASS];
    __shared__ int   cutbin_s, nIn_s, nBand_s;
    __shared__ int   bandI[BAND_CAP];
    __shared__ float bandKey[BAND_CAP];
    __shared__ float ssum;

    const int t = threadIdx.x;
    const int row = blockIdx.x;
    const unsigned int nlu = listCnt[row];
    const int nl = (int)(nlu < LIST_CAP ? nlu : LIST_CAP);
    const unsigned long long* lp = lists + (size_t)row * LIST_CAP;

    for (int i = t; i < HIST_SZ; i += 512) h[i] = 0;
    for (int i = t; i < DIM; i += 512) fsh[i] = feat[(size_t)row * DIM + i];
    for (int i = t; i < NCLASS; i += 512) p[i] = 0.f;
    if (t == 0) { cutbin_s = HIST_SZ - 1; nIn_s = 0; nBand_s = 0; }
    __syncthreads();

    // pass 1: histogram of floor(s)+64
    for (int i = t; i < nl; i += 512) {
        float s = __uint_as_float((unsigned)(lp[i] >> 32));
        int bin = (int)floorf(s) + 64;
        bin = bin < 0 ? 0 : (bin >= HIST_SZ ? HIST_SZ - 1 : bin);
        atomicAdd(&h[bin], 1u);
    }
    __syncthreads();

    // parallel cut-find
    if (t < HIST_SZ) {
        unsigned cum = 0;
        for (int b = 0; b <= t; ++b) cum += h[b];
        const unsigned cumPrev = cum - h[t];
        if (cum >= KNEIGH && cumPrev < KNEIGH) {
            cutbin_s = t;
            nIn_s = (int)(cumPrev - (t >= 1 ? h[t - 1] : 0u));
        }
    }
    __syncthreads();
    const int cutbin = cutbin_s;
    const int needB = KNEIGH - nIn_s;
    const float fnr = fnrep[row];

    // pass 2: def-in accumulate + band gather
    for (int i = t; i < nl; i += 512) {
        const unsigned long long e = lp[i];
        const float s = __uint_as_float((unsigned)(e >> 32));
        int bin = (int)floorf(s) + 64;
        bin = bin < 0 ? 0 : (bin >= HIST_SZ ? HIST_SZ - 1 : bin);
        if (bin <= cutbin - 2) {
            const int idx = (int)(unsigned)(e & 0xFFFFFFFFu);
            float wv = expf(kw[idx] - (fnr + s) * GC);
            atomicAdd(&p[labels[idx]], wv);
        } else if (bin <= cutbin + 1) {
            int pos = atomicAdd(&nBand_s, 1);
            if (pos < BAND_CAP) bandI[pos] = (int)(unsigned)(e & 0xFFFFFFFFu);
        }
    }
    __syncthreads();
    const int nBand = nBand_s < BAND_CAP ? nBand_s : BAND_CAP;

    // np-exact keys for band members
    for (int i = t; i < nBand; i += 512) {
        const int idx = bandI[i];
        const float* cp = cent + (size_t)idx * DIM;
        float acc = 0.f;
#pragma unroll
        for (int k = 0; k < DIM; ++k) acc = fmaf(2.0f * fsh[k], cp[k], acc);
        float cn = np_sum128_sq(cp);
        {
#pragma clang fp contract(off)
            bandKey[i] = (fnr - acc) + cn;
        }
    }
    __syncthreads();

    // take needB smallest (npKey, idx) from band
    for (int i = t; i < nBand; i += 512) {
        const float ki = bandKey[i];
        const int ii = bandI[i];
        int rank = 0;
        for (int j = 0; j < nBand; ++j) {
            float kj = bandKey[j];
            if (kj < ki || (kj == ki && bandI[j] < ii)) rank++;
        }
        if (rank < needB) {
            float wv = expf(kw[ii] - ki * GC);
            atomicAdd(&p[labels[ii]], wv);
        }
    }
    __syncthreads();

    // parallel normalize + log
    if (t < NCLASS) {
        float v = p[t];
        p[t] = (v == 0.f) ? 1e-10f : v;
    }
    __syncthreads();
    if (t < 64) {
        float v = p[t] + (t + 64 < NCLASS ? p[t + 64] : 0.f);
        v += __shfl_down(v, 32);
        v += __shfl_down(v, 16);
        v += __shfl_down(v, 8);
        v += __shfl_down(v, 4);
        v += __shfl_down(v, 2);
        v += __shfl_down(v, 1);
        if (t == 0) ssum = v;
    }
    __syncthreads();
    for (int c = t; c < NCLASS; c += 512)
        out[(size_t)row * NCLASS + c] = logf(p[c] / ssum);
}

static inline size_t align256(size_t x) { return (x + 255) & ~(size_t)255; }

extern "C" void kernel_launch(void* const* d_in, const int* in_sizes, int n_in,
                              void* d_out, int out_size, void* d_ws, size_t ws_size,
                              hipStream_t stream) {
    const float* feat   = (const float*)d_in[0];  // [1024,128]
    const float* cent   = (const float*)d_in[1];  // [100000,128]
    const float* kw     = (const float*)d_in[2];  // [100000]
    const int*   labels = (const int*)d_in[3];    // [100000]
    float* out = (float*)d_out;                   // [1024,100]

    char* base = (char*)d_ws;
    size_t o = 0;
    unsigned short* centb      = (unsigned short*)(base + o);      o += align256((size_t)NCENT * DIM * 2);
    unsigned short* featb      = (unsigned short*)(base + o);      o += align256((size_t)BATCH * DIM * 2);
    float* cnorm               = (float*)(base + o);               o += align256((size_t)NCENT * 4);
    float* fnrep               = (float*)(base + o);               o += align256((size_t)BATCH * 4);
    unsigned int* listCnt      = (unsigned int*)(base + o);        o += align256((size_t)BATCH * 4);
    unsigned long long* lists  = (unsigned long long*)(base + o);  o += align256((size_t)BATCH * LIST_CAP * 8);
    (void)ws_size; (void)in_sizes; (void)n_in; (void)out_size;

    prep_cent_kernel<<<NCENT / 32, 256, 0, stream>>>(cent, centb, cnorm);
    prep_feat_kernel<<<(BATCH + 255) / 256, 256, 0, stream>>>(feat, featb, fnrep, listCnt);

    dim3 gg((NCENT + 511) / 512, BATCH / ROWS_PB);   // 196 x 16
    mfma_coarse_kernel<<<gg, 256, 0, stream>>>(featb, centb, cnorm, lists, listCnt);

    select_refine_kernel<<<BATCH, 512, 0, stream>>>(lists, listCnt, feat, cent, fnrep,
                                                    kw, labels, out);
}

// Round 26
// 174.372 us; speedup vs baseline: 1.0092x; 1.0092x over previous
//
#include <hip/hip_runtime.h>
#include <cstdint>
#include <cstddef>

#define NCENT   100000
#define DIM     128
#define BATCH   1024
#define NCLASS  100
#define KNEIGH  200
#define GC      0.005f          // 1/(2*sigma^2), sigma=10
#define S_THR   75.0f           // static pre-filter on s; cut s in [38,58], slack >15
#define HIST_SZ 160
#define LIST_CAP 8192           // per-row list capacity; expected ~2800, worst ~4500
#define BAND_CAP 256            // band = 3 bins ~63-90 items; 256 ample
#define ROWS_PB  64             // rows per block in mfma (r19 proven)
#define LSLOTS   60             // per-(row,block) LDS slots + global fallback

typedef __attribute__((ext_vector_type(8))) short s8v;   // 8 bf16
typedef __attribute__((ext_vector_type(4))) float f4v;   // 4 f32 acc

static __device__ __forceinline__ unsigned short f2bf(float x) {
    uint32_t b = __float_as_uint(x);
    uint32_t r = (b + 0x7fffu + ((b >> 16) & 1u)) >> 16;   // RNE
    return (unsigned short)r;
}

// ---- replicate numpy AVX512 pairwise sum of x[k]^2, k=0..127 (round-3 verified) ----
__device__ __forceinline__ float np_sum128_sq(const float* __restrict__ x) {
#pragma clang fp contract(off)
    float v[16];
#pragma unroll
    for (int l = 0; l < 16; ++l) {
        float q0 = x[l]       * x[l];
        float q1 = x[16 + l]  * x[16 + l];
        float q2 = x[32 + l]  * x[32 + l];
        float q3 = x[48 + l]  * x[48 + l];
        float q4 = x[64 + l]  * x[64 + l];
        float q5 = x[80 + l]  * x[80 + l];
        float q6 = x[96 + l]  * x[96 + l];
        float q7 = x[112 + l] * x[112 + l];
        v[l] = ((q0 + q1) + (q2 + q3)) + ((q4 + q5) + (q6 + q7));
    }
    float t0 = v[0] + v[8],  t1 = v[1] + v[9],  t2 = v[2] + v[10], t3 = v[3] + v[11];
    float t4 = v[4] + v[12], t5 = v[5] + v[13], t6 = v[6] + v[14], t7 = v[7] + v[15];
    float u0 = t0 + t4, u1 = t1 + t5, u2 = t2 + t6, u3 = t3 + t7;
    float p0 = u0 + u2, p1 = u1 + u3;
    return p0 + p1;
}

// ---- prep: centres f32 -> bf16 + fp32 norms ----
__global__ __launch_bounds__(256) void prep_cent_kernel(
    const float* __restrict__ cent, unsigned short* __restrict__ centb,
    float* __restrict__ cnorm) {
    const int t = threadIdx.x;
    const int c = blockIdx.x * 32 + (t >> 3);
    const int p = t & 7;
    const float4* src = (const float4*)(cent + (size_t)c * DIM + p * 16);
    float s = 0.f;
    unsigned short tmp[16];
#pragma unroll
    for (int j = 0; j < 4; ++j) {
        float4 v = src[j];
        s += v.x * v.x + v.y * v.y + v.z * v.z + v.w * v.w;
        tmp[4 * j + 0] = f2bf(v.x); tmp[4 * j + 1] = f2bf(v.y);
        tmp[4 * j + 2] = f2bf(v.z); tmp[4 * j + 3] = f2bf(v.w);
    }
    s += __shfl_xor(s, 1); s += __shfl_xor(s, 2); s += __shfl_xor(s, 4);
    if (p == 0) cnorm[c] = s;
    uint4 o0, o1;
    o0.x = (uint32_t)tmp[0]  | ((uint32_t)tmp[1]  << 16);
    o0.y = (uint32_t)tmp[2]  | ((uint32_t)tmp[3]  << 16);
    o0.z = (uint32_t)tmp[4]  | ((uint32_t)tmp[5]  << 16);
    o0.w = (uint32_t)tmp[6]  | ((uint32_t)tmp[7]  << 16);
    o1.x = (uint32_t)tmp[8]  | ((uint32_t)tmp[9]  << 16);
    o1.y = (uint32_t)tmp[10] | ((uint32_t)tmp[11] << 16);
    o1.z = (uint32_t)tmp[12] | ((uint32_t)tmp[13] << 16);
    o1.w = (uint32_t)tmp[14] | ((uint32_t)tmp[15] << 16);
    uint4* dst = (uint4*)(centb + (size_t)c * DIM + p * 16);
    dst[0] = o0; dst[1] = o1;
}

// ---- prep: feat f32 -> bf16 + np-replicated |f|^2 per row; also zeroes listCnt ----
__global__ __launch_bounds__(256) void prep_feat_kernel(
    const float* __restrict__ feat, unsigned short* __restrict__ featb,
    float* __restrict__ fnrep, unsigned int* __restrict__ listCnt) {
    const int r = blockIdx.x * 256 + threadIdx.x;
    if (r >= BATCH) return;
    listCnt[r] = 0u;                     // replaces the separate hipMemsetAsync dispatch
    const float* fp = feat + (size_t)r * DIM;
    fnrep[r] = np_sum128_sq(fp);
    unsigned short* dst = featb + (size_t)r * DIM;
    for (int k = 0; k < DIM; ++k) dst[k] = f2bf(fp[k]);
}

// ---- coarse distance via bf16 MFMA (r22 champion: depth-1 prefetch, lazy-s epilogue) ----
// launch_bounds(256,3): 170-reg budget, no spill. Occupancy walls (measured):
//   (256,4) -> compiler squeezes to 64 VGPR and SPILLS (r23: WRITE 116MB, dur +4us)
//   more blocks/CU -> B-stripe L2 thrash (r12: FETCH 465MB)
//   depth-2 B pipe -> +regs +traffic (r21: +11us)
__global__ __launch_bounds__(256, 3) void mfma_coarse_kernel(
    const unsigned short* __restrict__ featb, const unsigned short* __restrict__ centb,
    const float* __restrict__ cnorm,
    unsigned long long* __restrict__ lists, unsigned int* __restrict__ listCnt) {
    __shared__ unsigned long long lbuf[ROWS_PB][LSLOTS];
    __shared__ unsigned int lcnt[ROWS_PB];
    __shared__ unsigned int gbase[ROWS_PB];
    __shared__ unsigned int gcnt[ROWS_PB];

    const int t = threadIdx.x;
    const int w = t >> 6;
    const int lane = t & 63;
    const int lrow = lane & 15;
    const int q = lane >> 4;
    const int lk = q * 8;
    const int row0 = blockIdx.y * ROWS_PB;
    const int colbase = blockIdx.x * 512;

    for (int i = t; i < ROWS_PB; i += 256) lcnt[i] = 0;

    s8v a[4][4];
#pragma unroll
    for (int rs = 0; rs < 4; ++rs)
#pragma unroll
        for (int ks = 0; ks < 4; ++ks)
            a[rs][ks] = *(const s8v*)(featb + (size_t)(row0 + rs * 16 + lrow) * DIM + ks * 32 + lk);

    __syncthreads();

    // prefetch it=0 B fragments + cnorm (depth-1, r20-proven)
    s8v b[4];
    float cn;
    {
        const int ccol = colbase + w * 16 + lrow;
        const int cc = ccol < NCENT ? ccol : NCENT - 1;
#pragma unroll
        for (int ks = 0; ks < 4; ++ks)
            b[ks] = *(const s8v*)(centb + (size_t)cc * DIM + ks * 32 + lk);
        cn = cnorm[cc];
    }

    for (int it = 0; it < 8; ++it) {
        const int ccol = colbase + it * 64 + w * 16 + lrow;
        const bool valid = (ccol < NCENT);

        s8v bc[4];
#pragma unroll
        for (int ks = 0; ks < 4; ++ks) bc[ks] = b[ks];
        const float cnc = cn;
        {
            const int itn = it + 1 < 8 ? it + 1 : 7;
            const int ccn = colbase + itn * 64 + w * 16 + lrow;
            const int cc2 = ccn < NCENT ? ccn : NCENT - 1;
#pragma unroll
            for (int ks = 0; ks < 4; ++ks)
                b[ks] = *(const s8v*)(centb + (size_t)cc2 * DIM + ks * 32 + lk);
            cn = cnorm[cc2];
        }

        f4v acc[4];
#pragma unroll
        for (int rs = 0; rs < 4; ++rs) acc[rs] = (f4v){0.f, 0.f, 0.f, 0.f};

#pragma unroll
        for (int ks = 0; ks < 4; ++ks) {
#pragma unroll
            for (int rs = 0; rs < 4; ++rs)
                acc[rs] = __builtin_amdgcn_mfma_f32_16x16x32_bf16(a[rs][ks], bc[ks], acc[rs], 0, 0, 0);
        }

        // epilogue: pass iff dot > (cn - S_THR)/2; s computed lazily for passers only
        const float thr = (cnc - S_THR) * 0.5f;
#pragma unroll
        for (int rs = 0; rs < 4; ++rs) {
#pragma unroll
            for (int j = 0; j < 4; ++j) {
                const float av = acc[rs][j];
                if (valid && av > thr) {            // ~2.8% of lanes
                    const float s = cnc - 2.0f * av;
                    const int lrowIdx = rs * 16 + q * 4 + j;
                    const unsigned long long val =
                        ((unsigned long long)__float_as_uint(s) << 32) | (unsigned)ccol;
                    unsigned pos = atomicAdd(&lcnt[lrowIdx], 1u);
                    if (pos < LSLOTS) {
                        lbuf[lrowIdx][pos] = val;
                    } else {
                        unsigned gp = atomicAdd(&listCnt[row0 + lrowIdx], 1u);
                        if (gp < LIST_CAP)
                            lists[(size_t)(row0 + lrowIdx) * LIST_CAP + gp] = val;
                    }
                }
            }
        }
    }
    __syncthreads();

    if (t < ROWS_PB) {
        unsigned c = lcnt[t];
        c = c < LSLOTS ? c : LSLOTS;
        gcnt[t] = c;
        gbase[t] = c ? atomicAdd(&listCnt[row0 + t], c) : 0u;
    }
    __syncthreads();
    {
        const int r = t >> 2, part = t & 3;
        const unsigned cnt = gcnt[r];
        for (unsigned sidx = (unsigned)part; sidx < cnt; sidx += 4) {
            const unsigned dstp = gbase[r] + sidx;
            if (dstp < LIST_CAP)
                lists[(size_t)(row0 + r) * LIST_CAP + dstp] = lbuf[r][sidx];
        }
    }
}

// ---- select+refine v3: bin-sandwich selection (r24 champion; (512,8) was null r25) ----
__global__ __launch_bounds__(512, 4) void select_refine_kernel(
    const unsigned long long* __restrict__ lists, const unsigned int* __restrict__ listCnt,
    const float* __restrict__ feat, const float* __restrict__ cent,
    const float* __restrict__ fnrep,
    const float* __restrict__ kw, const int* __restrict__ labels,
    float* __restrict__ out) {

    __shared__ unsigned int h[HIST_SZ];
    __shared__ float fsh[DIM];
    __shared__ float p[NCLASS];
    __shared__ int   cutbin_s, nIn_s, nBand_s;
    __shared__ int   bandI[BAND_CAP];
    __shared__ float bandKey[BAND_CAP];
    __shared__ float ssum;

    const int t = threadIdx.x;
    const int row = blockIdx.x;
    const unsigned int nlu = listCnt[row];
    const int nl = (int)(nlu < LIST_CAP ? nlu : LIST_CAP);
    const unsigned long long* lp = lists + (size_t)row * LIST_CAP;

    for (int i = t; i < HIST_SZ; i += 512) h[i] = 0;
    for (int i = t; i < DIM; i += 512) fsh[i] = feat[(size_t)row * DIM + i];
    for (int i = t; i < NCLASS; i += 512) p[i] = 0.f;
    if (t == 0) { cutbin_s = HIST_SZ - 1; nIn_s = 0; nBand_s = 0; }
    __syncthreads();

    // pass 1: histogram of floor(s)+64
    for (int i = t; i < nl; i += 512) {
        float s = __uint_as_float((unsigned)(lp[i] >> 32));
        int bin = (int)floorf(s) + 64;
        bin = bin < 0 ? 0 : (bin >= HIST_SZ ? HIST_SZ - 1 : bin);
        atomicAdd(&h[bin], 1u);
    }
    __syncthreads();

    // parallel cut-find
    if (t < HIST_SZ) {
        unsigned cum = 0;
        for (int b = 0; b <= t; ++b) cum += h[b];
        const unsigned cumPrev = cum - h[t];
        if (cum >= KNEIGH && cumPrev < KNEIGH) {
            cutbin_s = t;
            nIn_s = (int)(cumPrev - (t >= 1 ? h[t - 1] : 0u));
        }
    }
    __syncthreads();
    const int cutbin = cutbin_s;
    const int needB = KNEIGH - nIn_s;
    const float fnr = fnrep[row];

    // pass 2: def-in accumulate + band gather
    for (int i = t; i < nl; i += 512) {
        const unsigned long long e = lp[i];
        const float s = __uint_as_float((unsigned)(e >> 32));
        int bin = (int)floorf(s) + 64;
        bin = bin < 0 ? 0 : (bin >= HIST_SZ ? HIST_SZ - 1 : bin);
        if (bin <= cutbin - 2) {
            const int idx = (int)(unsigned)(e & 0xFFFFFFFFu);
            float wv = expf(kw[idx] - (fnr + s) * GC);
            atomicAdd(&p[labels[idx]], wv);
        } else if (bin <= cutbin + 1) {
            int pos = atomicAdd(&nBand_s, 1);
            if (pos < BAND_CAP) bandI[pos] = (int)(unsigned)(e & 0xFFFFFFFFu);
        }
    }
    __syncthreads();
    const int nBand = nBand_s < BAND_CAP ? nBand_s : BAND_CAP;

    // np-exact keys for band members
    for (int i = t; i < nBand; i += 512) {
        const int idx = bandI[i];
        const float* cp = cent + (size_t)idx * DIM;
        float acc = 0.f;
#pragma unroll
        for (int k = 0; k < DIM; ++k) acc = fmaf(2.0f * fsh[k], cp[k], acc);
        float cn = np_sum128_sq(cp);
        {
#pragma clang fp contract(off)
            bandKey[i] = (fnr - acc) + cn;
        }
    }
    __syncthreads();

    // take needB smallest (npKey, idx) from band
    for (int i = t; i < nBand; i += 512) {
        const float ki = bandKey[i];
        const int ii = bandI[i];
        int rank = 0;
        for (int j = 0; j < nBand; ++j) {
            float kj = bandKey[j];
            if (kj < ki || (kj == ki && bandI[j] < ii)) rank++;
        }
        if (rank < needB) {
            float wv = expf(kw[ii] - ki * GC);
            atomicAdd(&p[labels[ii]], wv);
        }
    }
    __syncthreads();

    // parallel normalize + log
    if (t < NCLASS) {
        float v = p[t];
        p[t] = (v == 0.f) ? 1e-10f : v;
    }
    __syncthreads();
    if (t < 64) {
        float v = p[t] + (t + 64 < NCLASS ? p[t + 64] : 0.f);
        v += __shfl_down(v, 32);
        v += __shfl_down(v, 16);
        v += __shfl_down(v, 8);
        v += __shfl_down(v, 4);
        v += __shfl_down(v, 2);
        v += __shfl_down(v, 1);
        if (t == 0) ssum = v;
    }
    __syncthreads();
    for (int c = t; c < NCLASS; c += 512)
        out[(size_t)row * NCLASS + c] = logf(p[c] / ssum);
}

static inline size_t align256(size_t x) { return (x + 255) & ~(size_t)255; }

extern "C" void kernel_launch(void* const* d_in, const int* in_sizes, int n_in,
                              void* d_out, int out_size, void* d_ws, size_t ws_size,
                              hipStream_t stream) {
    const float* feat   = (const float*)d_in[0];  // [1024,128]
    const float* cent   = (const float*)d_in[1];  // [100000,128]
    const float* kw     = (const float*)d_in[2];  // [100000]
    const int*   labels = (const int*)d_in[3];    // [100000]
    float* out = (float*)d_out;                   // [1024,100]

    char* base = (char*)d_ws;
    size_t o = 0;
    unsigned short* centb      = (unsigned short*)(base + o);      o += align256((size_t)NCENT * DIM * 2);
    unsigned short* featb      = (unsigned short*)(base + o);      o += align256((size_t)BATCH * DIM * 2);
    float* cnorm               = (float*)(base + o);               o += align256((size_t)NCENT * 4);
    float* fnrep               = (float*)(base + o);               o += align256((size_t)BATCH * 4);
    unsigned int* listCnt      = (unsigned int*)(base + o);        o += align256((size_t)BATCH * 4);
    unsigned long long* lists  = (unsigned long long*)(base + o);  o += align256((size_t)BATCH * LIST_CAP * 8);
    (void)ws_size; (void)in_sizes; (void)n_in; (void)out_size;

    prep_cent_kernel<<<NCENT / 32, 256, 0, stream>>>(cent, centb, cnorm);
    prep_feat_kernel<<<(BATCH + 255) / 256, 256, 0, stream>>>(feat, featb, fnrep, listCnt);

    dim3 gg((NCENT + 511) / 512, BATCH / ROWS_PB);   // 196 x 16
    mfma_coarse_kernel<<<gg, 256, 0, stream>>>(featb, centb, cnorm, lists, listCnt);

    select_refine_kernel<<<BATCH, 512, 0, stream>>>(lists, listCnt, feat, cent, fnrep,
                                                    kw, labels, out);
}